// Round 5
// baseline (424.633 us; speedup 1.0000x reference)
//
#include <hip/hip_runtime.h>
#include <hip/hip_bf16.h>
#include <cstdint>

typedef unsigned short u16;
typedef __attribute__((ext_vector_type(8))) short bf16x8;
typedef __attribute__((ext_vector_type(4))) float f32x4;

#define T_SEQ 2048
#define NHEAD 16
#define HDIM  64
#define NB    2

__device__ __forceinline__ float bf2f(uint32_t h) { return __uint_as_float(h << 16); }
__device__ __forceinline__ u16 f2bf(float f) {
    uint32_t u = __float_as_uint(f);
    u += 0x7fffu + ((u >> 16) & 1u);
    return (u16)(u >> 16);
}

// Detect input dtype: bf16-packed data has low-u16 exponent fields clustered
// near 127; fp32 low halves are ~uniform mantissa bits.
__global__ void detect_dtype(const uint32_t* __restrict__ x, int* __restrict__ flag) {
    if (threadIdx.x == 0 && blockIdx.x == 0) {
        int cnt = 0;
        for (int i = 0; i < 1024; i++) {
            uint32_t lo = x[i] & 0xffffu;
            uint32_t e = (lo >> 7) & 0xffu;
            if (lo != 0u && e >= 110u && e <= 135u) cnt++;
        }
        *flag = (cnt > 614) ? 1 : 0;   // 1 = inputs bf16, 0 = fp32
    }
}

__global__ __launch_bounds__(256) void to_bf16(
    const void* __restrict__ src, u16* __restrict__ dst, int n,
    const int* __restrict__ flag)
{
    const bool isbf = (*flag != 0);
    int i = blockIdx.x * blockDim.x + threadIdx.x;
    const int stride = gridDim.x * blockDim.x;
    if (isbf) {
        const u16* s = (const u16*)src;
        for (; i < n; i += stride) dst[i] = s[i];
    } else {
        const float* s = (const float*)src;
        for (; i < n; i += stride) dst[i] = f2bf(s[i]);
    }
}

// Pipelined MFMA GEMM: C = A (MxK bf16 rm) * B^T (B NxK rm), fp32 accum.
// BMxBM tile, 4 waves in 2x2, each wave (BM/2)^2 via 16x16x32 MFMA.
// Epilogues go through a per-wave LDS transpose so every global store
// instruction writes full 128B lines (8 lanes x 16B contiguous).
// MODE 0 (BM=128): scatter q [b,h,t,d] (x0.125), k [b,h,t,d], vT [b,h,d,t].
// MODE 1: row-major C; bf16 fast path, fp32 scalar fallback per *flag.
template<int BM, int MODE>
__global__ __launch_bounds__(256) void gemm_bt_mfma(
    const u16* __restrict__ A, const u16* __restrict__ B,
    int N, int K,
    u16* __restrict__ qo, u16* __restrict__ ko, u16* __restrict__ vt,
    u16* __restrict__ outb16, float* __restrict__ outf32,
    const int* __restrict__ flag)
{
    constexpr int BN = BM;
    constexpr int WM = BM / 2, WN = BN / 2;
    constexpr int MI = WM / 16, NI = WN / 16;
    constexpr int LA = BM / 32, LB = BN / 32;
    __shared__ u16 smem[(BM + BN) * 72];
    u16* As = smem;            // [BM][72]
    u16* Bs = smem + BM * 72;  // [BN][72]
    const int tid = threadIdx.x;
    const int bm = blockIdx.y * BM, bn = blockIdx.x * BN;
    const int w = tid >> 6, lane = tid & 63;
    const int wm = (w >> 1) * WM, wn = (w & 1) * WN;
    const int n16 = lane & 15, quad = lane >> 4;

    f32x4 acc[MI][NI];
#pragma unroll
    for (int mi = 0; mi < MI; mi++)
#pragma unroll
        for (int ni = 0; ni < NI; ni++) acc[mi][ni] = (f32x4){0.f, 0.f, 0.f, 0.f};

    const int KT = K >> 6;
    uint4 abuf[LA], bbuf[LB];

    auto loadg = [&](int k0) {
#pragma unroll
        for (int i = 0; i < LA; i++) {
            int u = tid + i * 256;
            abuf[i] = *(const uint4*)(A + (size_t)(bm + (u >> 3)) * K + k0 + (u & 7) * 8);
        }
#pragma unroll
        for (int i = 0; i < LB; i++) {
            int u = tid + i * 256;
            bbuf[i] = *(const uint4*)(B + (size_t)(bn + (u >> 3)) * K + k0 + (u & 7) * 8);
        }
    };
    auto compute = [&]() {
#pragma unroll
        for (int ks = 0; ks < 2; ks++) {
            bf16x8 af[MI], bfr[NI];
#pragma unroll
            for (int mi = 0; mi < MI; mi++)
                af[mi] = *(const bf16x8*)(As + (wm + mi * 16 + n16) * 72 + ks * 32 + quad * 8);
#pragma unroll
            for (int ni = 0; ni < NI; ni++)
                bfr[ni] = *(const bf16x8*)(Bs + (wn + ni * 16 + n16) * 72 + ks * 32 + quad * 8);
#pragma unroll
            for (int mi = 0; mi < MI; mi++)
#pragma unroll
                for (int ni = 0; ni < NI; ni++)
                    acc[mi][ni] = __builtin_amdgcn_mfma_f32_16x16x32_bf16(
                        af[mi], bfr[ni], acc[mi][ni], 0, 0, 0);
        }
    };

    loadg(0);
    for (int kt = 0; kt < KT; kt++) {
        if (kt > 0) compute();
        __syncthreads();
#pragma unroll
        for (int i = 0; i < LA; i++) {
            int u = tid + i * 256;
            *(uint4*)(As + (u >> 3) * 72 + (u & 7) * 8) = abuf[i];
        }
#pragma unroll
        for (int i = 0; i < LB; i++) {
            int u = tid + i * 256;
            *(uint4*)(Bs + (u >> 3) * 72 + (u & 7) * 8) = bbuf[i];
        }
        __syncthreads();
        if (kt + 1 < KT) loadg((kt + 1) << 6);   // lands during next compute()
    }
    compute();

    __syncthreads();   // all waves done reading K-loop LDS; reuse as epilogue buffer
    u16* ep = smem + w * (WM * 72);   // per-wave [WM][72]

    if constexpr (MODE == 0) {
        const int which = (bn + wn) >> 10;            // wave-uniform: 0=q 1=k 2=v
        const int hq = ((bn + wn) & 1023) >> 6;       // head (n-range is 64-aligned)
        const int bb = (bm + wm) >> 11;               // batch (m-range 64-aligned)
        const int tb = (bm + wm) & (T_SEQ - 1);
        if (which == 2) {
            // transpose in LDS: ep[n_local][m_local] -> rows are d, cols are t
#pragma unroll
            for (int mi = 0; mi < MI; mi++)
#pragma unroll
                for (int ni = 0; ni < NI; ni++)
#pragma unroll
                    for (int r = 0; r < 4; r++)
                        ep[(ni * 16 + n16) * 72 + mi * 16 + quad * 4 + r] = f2bf(acc[mi][ni][r]);
            asm volatile("s_waitcnt lgkmcnt(0)" ::: "memory");
            u16* dst = vt + ((size_t)(bb * NHEAD + hq) * HDIM) * T_SEQ + tb;
#pragma unroll
            for (int it = 0; it < 8; it++) {
                int row = it * 8 + (lane >> 3), col = (lane & 7) * 8;
                bf16x8 v = *(const bf16x8*)(ep + row * 72 + col);
                *(bf16x8*)(dst + (size_t)row * T_SEQ + col) = v;   // 8 lanes = 128B line
            }
        } else {
            const float sc = which ? 1.f : 0.125f;
#pragma unroll
            for (int mi = 0; mi < MI; mi++)
#pragma unroll
                for (int ni = 0; ni < NI; ni++)
#pragma unroll
                    for (int r = 0; r < 4; r++)
                        ep[(mi * 16 + quad * 4 + r) * 72 + ni * 16 + n16] = f2bf(acc[mi][ni][r] * sc);
            asm volatile("s_waitcnt lgkmcnt(0)" ::: "memory");
            u16* dst = (which ? ko : qo) + ((size_t)(bb * NHEAD + hq) * T_SEQ + tb) * HDIM;
#pragma unroll
            for (int it = 0; it < 8; it++) {
                int row = it * 8 + (lane >> 3), col = (lane & 7) * 8;
                bf16x8 v = *(const bf16x8*)(ep + row * 72 + col);
                *(bf16x8*)(dst + (size_t)row * HDIM + col) = v;    // 8 lanes = 128B line
            }
        }
    } else {
        if (*flag != 0) {
#pragma unroll
            for (int mi = 0; mi < MI; mi++)
#pragma unroll
                for (int ni = 0; ni < NI; ni++)
#pragma unroll
                    for (int r = 0; r < 4; r++)
                        ep[(mi * 16 + quad * 4 + r) * 72 + ni * 16 + n16] = f2bf(acc[mi][ni][r]);
            asm volatile("s_waitcnt lgkmcnt(0)" ::: "memory");
            constexpr int LPR = WN / 8;                 // lanes per row
            constexpr int RPI = 64 / LPR;               // rows per instruction
            constexpr int ITERS = WM / RPI;
#pragma unroll
            for (int it = 0; it < ITERS; it++) {
                int row = it * RPI + lane / LPR, col = (lane % LPR) * 8;
                bf16x8 v = *(const bf16x8*)(ep + row * 72 + col);
                *(bf16x8*)(outb16 + (size_t)(bm + wm + row) * N + bn + wn + col) = v;
            }
        } else {
            // fp32 fallback (correctness path only)
#pragma unroll
            for (int mi = 0; mi < MI; mi++)
#pragma unroll
                for (int ni = 0; ni < NI; ni++)
#pragma unroll
                    for (int r = 0; r < 4; r++)
                        outf32[(size_t)(bm + wm + mi * 16 + quad * 4 + r) * N
                               + bn + wn + ni * 16 + n16] = acc[mi][ni][r];
        }
    }
}

// MFMA flash attention, max-free softmax (p = exp(s-10); offset cancels in
// o/l). Row denominators via mfma(P, ones). Blocks pair q-tiles (i, NT-1-i).
// K [b,h,t,d] and V^T [b,h,d,t] fragments load straight from global.
// Output goes through the per-wave LDS transpose -> full-line 16B stores.
__global__ __launch_bounds__(256) void attn_mfma(
    const u16* __restrict__ qb, const u16* __restrict__ kb,
    const u16* __restrict__ vt, u16* __restrict__ ob)
{
    __shared__ u16 Plds[4][16][72];
    const int pair = blockIdx.x;           // 0..NT/2-1
    const int bh = blockIdx.y;
    const int w = threadIdx.x >> 6, lane = threadIdx.x & 63;
    const int n16 = lane & 15, quad = lane >> 4;
    const size_t baseK = (size_t)bh * T_SEQ * HDIM;   // [t][d]
    const size_t baseV = (size_t)bh * HDIM * T_SEQ;   // [d][t]
    const int NT = T_SEQ / 64;             // 32
    const int b = bh >> 4, h = bh & 15;

    bf16x8 ones;
#pragma unroll
    for (int j = 0; j < 8; j++) ones[j] = (short)0x3F80;   // bf16 1.0

    for (int half = 0; half < 2; half++) {
        const int qt = half ? pair : (NT - 1 - pair);   // big tile first
        const int qrow = qt * 64 + w * 16;

        bf16x8 qf[2];
#pragma unroll
        for (int ks = 0; ks < 2; ks++)
            qf[ks] = *(const bf16x8*)(qb + baseK + (size_t)(qrow + n16) * HDIM + ks * 32 + quad * 8);

        f32x4 accO[4];
#pragma unroll
        for (int st = 0; st < 4; st++) accO[st] = (f32x4){0.f, 0.f, 0.f, 0.f};
        f32x4 accL = (f32x4){0.f, 0.f, 0.f, 0.f};

        bf16x8 kf[2][4];
#pragma unroll
        for (int st = 0; st < 4; st++)
#pragma unroll
            for (int ks = 0; ks < 2; ks++)
                kf[ks][st] = *(const bf16x8*)(kb + baseK + (size_t)(st * 16 + n16) * HDIM + ks * 32 + quad * 8);

        for (int kt = 0; kt <= qt; kt++) {
            bf16x8 vf[2][4];
            const u16* vbase = vt + baseV + kt * 64;
#pragma unroll
            for (int st = 0; st < 4; st++)
#pragma unroll
                for (int ks = 0; ks < 2; ks++)
                    vf[ks][st] = *(const bf16x8*)(vbase + (size_t)(st * 16 + n16) * T_SEQ + ks * 32 + quad * 8);

            f32x4 S[4];
#pragma unroll
            for (int st = 0; st < 4; st++) S[st] = (f32x4){0.f, 0.f, 0.f, 0.f};
#pragma unroll
            for (int st = 0; st < 4; st++)
#pragma unroll
                for (int ks = 0; ks < 2; ks++)
                    S[st] = __builtin_amdgcn_mfma_f32_16x16x32_bf16(qf[ks], kf[ks][st], S[st], 0, 0, 0);

            if (kt < qt) {   // prefetch next K under softmax
                const u16* kbase = kb + baseK + (size_t)(kt + 1) * 64 * HDIM;
#pragma unroll
                for (int st = 0; st < 4; st++)
#pragma unroll
                    for (int ks = 0; ks < 2; ks++)
                        kf[ks][st] = *(const bf16x8*)(kbase + (st * 16 + n16) * HDIM + ks * 32 + quad * 8);
            }

            if (kt == qt) {   // diagonal tile: causal mask
                int qloc = w * 16 + quad * 4;
#pragma unroll
                for (int st = 0; st < 4; st++) {
                    int kloc = st * 16 + n16;
#pragma unroll
                    for (int r = 0; r < 4; r++)
                        if (kloc > qloc + r) S[st][r] = -INFINITY;
                }
            }

            // p = exp(s - 10) = exp2(1.4427*s - 14.427); offset cancels in o/l
#pragma unroll
            for (int st = 0; st < 4; st++)
#pragma unroll
                for (int r = 0; r < 4; r++) {
                    float p = exp2f(__builtin_fmaf(S[st][r], 1.44269504f, -14.4269504f));
                    Plds[w][quad * 4 + r][st * 16 + n16] = f2bf(p);
                }
            asm volatile("s_waitcnt lgkmcnt(0)" ::: "memory");
            bf16x8 pf[2];
#pragma unroll
            for (int ks = 0; ks < 2; ks++)
                pf[ks] = *(const bf16x8*)(&Plds[w][n16][ks * 32 + quad * 8]);

#pragma unroll
            for (int st = 0; st < 4; st++)
#pragma unroll
                for (int ks = 0; ks < 2; ks++)
                    accO[st] = __builtin_amdgcn_mfma_f32_16x16x32_bf16(pf[ks], vf[ks][st], accO[st], 0, 0, 0);
#pragma unroll
            for (int ks = 0; ks < 2; ks++)
                accL = __builtin_amdgcn_mfma_f32_16x16x32_bf16(pf[ks], ones, accL, 0, 0, 0);
        }

        // epilogue: normalize, transpose via Plds, full-line stores
#pragma unroll
        for (int r = 0; r < 4; r++) {
            float inv = 1.f / accL[r];
#pragma unroll
            for (int st = 0; st < 4; st++)
                Plds[w][quad * 4 + r][st * 16 + n16] = f2bf(accO[st][r] * inv);
        }
        asm volatile("s_waitcnt lgkmcnt(0)" ::: "memory");
        u16* dst = ob + ((size_t)(b * T_SEQ + qrow)) * 1024 + h * HDIM;
#pragma unroll
        for (int it = 0; it < 2; it++) {
            int row = it * 8 + (lane >> 3), col = (lane & 7) * 8;
            bf16x8 v = *(const bf16x8*)(&Plds[w][row][col]);
            *(bf16x8*)(dst + (size_t)row * 1024 + col) = v;   // 8 lanes = 128B line
        }
    }
}

extern "C" void kernel_launch(void* const* d_in, const int* in_sizes, int n_in,
                              void* d_out, int out_size, void* d_ws, size_t ws_size,
                              hipStream_t stream) {
    const void* x    = d_in[0];   // (2,2048,1024)
    const void* Wqkv = d_in[1];   // (3072,1024)
    const void* Wout = d_in[2];   // (1024,1024)

    const int Mtok = NB * T_SEQ;                                  // 4096
    const size_t n_x    = (size_t)Mtok * 1024;
    const size_t n_wqkv = (size_t)3072 * 1024;
    const size_t n_wout = (size_t)1024 * 1024;
    const size_t qkv_elems = (size_t)NB * NHEAD * T_SEQ * HDIM;   // 4,194,304

    u16* xb    = (u16*)d_ws;
    u16* wqkvb = xb + n_x;
    u16* woutb = wqkvb + n_wqkv;
    u16* qb    = woutb + n_wout;
    u16* kb    = qb + qkv_elems;
    u16* vt    = kb + qkv_elems;   // V stored transposed [b,h,d,t]
    u16* obuf  = vt + qkv_elems;
    int* flag  = (int*)(obuf + qkv_elems);

    detect_dtype<<<1, 64, 0, stream>>>((const uint32_t*)x, flag);

    to_bf16<<<2048, 256, 0, stream>>>(x,    xb,    (int)n_x,    flag);
    to_bf16<<<2048, 256, 0, stream>>>(Wqkv, wqkvb, (int)n_wqkv, flag);
    to_bf16<<<1024, 256, 0, stream>>>(Wout, woutb, (int)n_wout, flag);

    gemm_bt_mfma<128, 0><<<dim3(3072 / 128, Mtok / 128), 256, 0, stream>>>(
        xb, wqkvb, 3072, 1024, qb, kb, vt, nullptr, nullptr, flag);

    attn_mfma<<<dim3(T_SEQ / 128, NB * NHEAD), 256, 0, stream>>>(qb, kb, vt, obuf);

    gemm_bt_mfma<64, 1><<<dim3(1024 / 64, Mtok / 64), 256, 0, stream>>>(
        obuf, woutb, 1024, 1024, nullptr, nullptr, nullptr,
        (u16*)d_out, (float*)d_out, flag);
}

// Round 6
// 382.069 us; speedup vs baseline: 1.1114x; 1.1114x over previous
//
#include <hip/hip_runtime.h>
#include <hip/hip_bf16.h>
#include <cstdint>

typedef unsigned short u16;
typedef __attribute__((ext_vector_type(8))) short bf16x8;
typedef __attribute__((ext_vector_type(4))) float f32x4;

#define T_SEQ 2048
#define NHEAD 16
#define HDIM  64
#define NB    2

__device__ __forceinline__ float bf2f(uint32_t h) { return __uint_as_float(h << 16); }
__device__ __forceinline__ u16 f2bf(float f) {
    uint32_t u = __float_as_uint(f);
    u += 0x7fffu + ((u >> 16) & 1u);
    return (u16)(u >> 16);
}

// async global->LDS, 16B per lane; LDS dest = wave-uniform base + lane*16
__device__ __forceinline__ void gl_lds16(const u16* g, u16* s) {
    __builtin_amdgcn_global_load_lds(
        (const __attribute__((address_space(1))) unsigned int*)g,
        (__attribute__((address_space(3))) unsigned int*)s, 16, 0, 0);
}

// Detect input dtype: bf16-packed data has low-u16 exponent fields clustered
// near 127; fp32 low halves are ~uniform mantissa bits.
__global__ void detect_dtype(const uint32_t* __restrict__ x, int* __restrict__ flag) {
    if (threadIdx.x == 0 && blockIdx.x == 0) {
        int cnt = 0;
        for (int i = 0; i < 1024; i++) {
            uint32_t lo = x[i] & 0xffffu;
            uint32_t e = (lo >> 7) & 0xffu;
            if (lo != 0u && e >= 110u && e <= 135u) cnt++;
        }
        *flag = (cnt > 614) ? 1 : 0;   // 1 = inputs bf16, 0 = fp32
    }
}

// vectorized conversion, 4 elements per thread
__global__ __launch_bounds__(256) void to_bf16(
    const void* __restrict__ src, u16* __restrict__ dst, int n4,
    const int* __restrict__ flag)
{
    int i = blockIdx.x * 256 + threadIdx.x;
    const int stride = gridDim.x * 256;
    if (*flag != 0) {
        const uint2* s = (const uint2*)src;
        uint2* d = (uint2*)dst;
        for (; i < n4; i += stride) d[i] = s[i];
    } else {
        const float4* s = (const float4*)src;
        for (; i < n4; i += stride) {
            float4 v = s[i];
            ushort4 o = { f2bf(v.x), f2bf(v.y), f2bf(v.z), f2bf(v.w) };
            *(ushort4*)(dst + (size_t)i * 4) = o;
        }
    }
}

// m97-pattern MFMA GEMM: C = A (MxK bf16 rm) * B^T (B NxK rm), fp32 accum.
// global_load_lds width-16 staging into unpadded [BM][64] LDS tiles with XOR
// swizzle (LDS chunk c of row r holds global chunk c^(r&7)) -> conflict-free
// stride-64 fragment reads. 4 waves in 2x2, no register staging buffers.
// MODE 0 (BM=128): scatter q [b,h,t,d] (x0.125), k [b,h,t,d], vT [b,h,d,t].
// MODE 1 (BM=64): row-major C; fp32 (flag==0) or bf16 path, full-line stores.
template<int BM, int MODE>
__global__ __launch_bounds__(256, 3) void gemm_bt_mfma(
    const u16* __restrict__ A, const u16* __restrict__ B,
    int N, int K,
    u16* __restrict__ qo, u16* __restrict__ ko, u16* __restrict__ vt,
    u16* __restrict__ outb16, float* __restrict__ outf32,
    const int* __restrict__ flag)
{
    constexpr int WM = BM / 2;
    constexpr int MI = WM / 16;
    constexpr int IA = BM / 32;   // global_load_lds instrs per wave per matrix
    constexpr int ST = 2 * BM * 64 * 2;                       // staging bytes
    constexpr int E16 = 4 * WM * 72 * 2;                      // u16 epilogue bytes
    constexpr int EF = (MODE == 1) ? 4 * WM * (WM + 4) * 4 : 0;  // f32 epilogue
    constexpr int SB = (ST > E16 ? ST : E16) > EF ? (ST > E16 ? ST : E16) : EF;
    __shared__ u16 smem[SB / 2];
    u16* As = smem;            // [BM][64]
    u16* Bs = smem + BM * 64;  // [BM][64]
    const int tid = threadIdx.x;
    const int bm = blockIdx.y * BM, bn = blockIdx.x * BM;
    const int w = tid >> 6, lane = tid & 63;
    const int wm = (w >> 1) * WM, wn = (w & 1) * WM;
    const int n16 = lane & 15, quad = lane >> 4;
    const int l8 = lane >> 3, c8 = lane & 7;

    f32x4 acc[MI][MI];
#pragma unroll
    for (int mi = 0; mi < MI; mi++)
#pragma unroll
        for (int ni = 0; ni < MI; ni++) acc[mi][ni] = (f32x4){0.f, 0.f, 0.f, 0.f};

    const int KT = K >> 6;
    for (int kt = 0; kt < KT; kt++) {
        const int k0 = kt << 6;
#pragma unroll
        for (int i = 0; i < IA; i++) {
            int rowblk = (i * 4 + w) * 8;
            int row = rowblk + l8;
            int gcol = (c8 ^ l8) * 8;   // XOR swizzle: LDS chunk c holds global chunk c^(row&7)
            gl_lds16(A + (size_t)(bm + row) * K + k0 + gcol, As + rowblk * 64);
            gl_lds16(B + (size_t)(bn + row) * K + k0 + gcol, Bs + rowblk * 64);
        }
        __syncthreads();   // drains vmcnt before barrier
#pragma unroll
        for (int ks = 0; ks < 2; ks++) {
            bf16x8 af[MI], bfr[MI];
#pragma unroll
            for (int mi = 0; mi < MI; mi++) {
                int row = wm + mi * 16 + n16;
                af[mi] = *(const bf16x8*)(As + row * 64 + (((ks * 4 + quad) ^ (n16 & 7)) * 8));
            }
#pragma unroll
            for (int ni = 0; ni < MI; ni++) {
                int row = wn + ni * 16 + n16;
                bfr[ni] = *(const bf16x8*)(Bs + row * 64 + (((ks * 4 + quad) ^ (n16 & 7)) * 8));
            }
#pragma unroll
            for (int mi = 0; mi < MI; mi++)
#pragma unroll
                for (int ni = 0; ni < MI; ni++)
                    acc[mi][ni] = __builtin_amdgcn_mfma_f32_16x16x32_bf16(
                        af[mi], bfr[ni], acc[mi][ni], 0, 0, 0);
        }
        __syncthreads();   // all reads done before next stage overwrites
    }

    // Epilogues: per-wave LDS transpose -> full-line stores.
    // C/D layout: col = n16, row = quad*4 + r (HW-verified m89/m91).
    if constexpr (MODE == 0) {
        u16* ep = smem + w * (WM * 72);
        const int which = (bn + wn) >> 10;            // wave-uniform: 0=q 1=k 2=v
        const int hq = ((bn + wn) & 1023) >> 6;
        const int bb = (bm + wm) >> 11;
        const int tb = (bm + wm) & (T_SEQ - 1);
        if (which == 2) {
            // transpose: ep rows are d, cols are t
#pragma unroll
            for (int mi = 0; mi < MI; mi++)
#pragma unroll
                for (int ni = 0; ni < MI; ni++)
#pragma unroll
                    for (int r = 0; r < 4; r++)
                        ep[(ni * 16 + n16) * 72 + mi * 16 + quad * 4 + r] = f2bf(acc[mi][ni][r]);
            asm volatile("s_waitcnt lgkmcnt(0)" ::: "memory");
            u16* dst = vt + ((size_t)(bb * NHEAD + hq) * HDIM) * T_SEQ + tb;
#pragma unroll
            for (int it = 0; it < 8; it++) {
                int row = it * 8 + l8, col = c8 * 8;
                bf16x8 v = *(const bf16x8*)(ep + row * 72 + col);
                *(bf16x8*)(dst + (size_t)row * T_SEQ + col) = v;
            }
        } else {
            const float sc = which ? 1.f : 0.125f;
#pragma unroll
            for (int mi = 0; mi < MI; mi++)
#pragma unroll
                for (int ni = 0; ni < MI; ni++)
#pragma unroll
                    for (int r = 0; r < 4; r++)
                        ep[(mi * 16 + quad * 4 + r) * 72 + ni * 16 + n16] = f2bf(acc[mi][ni][r] * sc);
            asm volatile("s_waitcnt lgkmcnt(0)" ::: "memory");
            u16* dst = (which ? ko : qo) + ((size_t)(bb * NHEAD + hq) * T_SEQ + tb) * HDIM;
#pragma unroll
            for (int it = 0; it < 8; it++) {
                int row = it * 8 + l8, col = c8 * 8;
                bf16x8 v = *(const bf16x8*)(ep + row * 72 + col);
                *(bf16x8*)(dst + (size_t)row * HDIM + col) = v;
            }
        }
    } else {
        if (*flag == 0) {
            // fp32 output (live path): float4 full-line stores via LDS transpose
            float* epf = (float*)smem + w * (WM * (WM + 4));
#pragma unroll
            for (int mi = 0; mi < MI; mi++)
#pragma unroll
                for (int ni = 0; ni < MI; ni++)
#pragma unroll
                    for (int r = 0; r < 4; r++)
                        epf[(mi * 16 + quad * 4 + r) * (WM + 4) + ni * 16 + n16] = acc[mi][ni][r];
            asm volatile("s_waitcnt lgkmcnt(0)" ::: "memory");
            constexpr int LPR = WM / 4;                 // lanes per row (float4)
            constexpr int RPI = 64 / LPR;               // rows per instruction
#pragma unroll
            for (int it = 0; it < WM / RPI; it++) {
                int row = it * RPI + lane / LPR, col = (lane % LPR) * 4;
                float4 v = *(const float4*)(epf + row * (WM + 4) + col);
                *(float4*)(outf32 + (size_t)(bm + wm + row) * N + bn + wn + col) = v;
            }
        } else {
            u16* ep = smem + w * (WM * 72);
#pragma unroll
            for (int mi = 0; mi < MI; mi++)
#pragma unroll
                for (int ni = 0; ni < MI; ni++)
#pragma unroll
                    for (int r = 0; r < 4; r++)
                        ep[(mi * 16 + quad * 4 + r) * 72 + ni * 16 + n16] = f2bf(acc[mi][ni][r]);
            asm volatile("s_waitcnt lgkmcnt(0)" ::: "memory");
            constexpr int LPR = WM / 8;
            constexpr int RPI = 64 / LPR;
#pragma unroll
            for (int it = 0; it < WM / RPI; it++) {
                int row = it * RPI + lane / LPR, col = (lane % LPR) * 8;
                bf16x8 v = *(const bf16x8*)(ep + row * 72 + col);
                *(bf16x8*)(outb16 + (size_t)(bm + wm + row) * N + bn + wn + col) = v;
            }
        }
    }
}

// MFMA flash attention, max-free softmax (p = exp(s-10); offset cancels in
// o/l). Row denominators via mfma(P, ones). Grid (NT, BH) unpaired, qt
// descending so big tiles start first. P repack uses 1-op truncation (bias
// cancels between numerator and ones-MFMA denominator).
__global__ __launch_bounds__(256) void attn_mfma(
    const u16* __restrict__ qb, const u16* __restrict__ kb,
    const u16* __restrict__ vt, u16* __restrict__ ob)
{
    __shared__ u16 Plds[4][16][72];
    const int qt = (int)gridDim.x - 1 - (int)blockIdx.x;
    const int bh = blockIdx.y;
    const int w = threadIdx.x >> 6, lane = threadIdx.x & 63;
    const int n16 = lane & 15, quad = lane >> 4;
    const size_t baseK = (size_t)bh * T_SEQ * HDIM;   // [t][d]
    const size_t baseV = (size_t)bh * HDIM * T_SEQ;   // [d][t]
    const int b = bh >> 4, h = bh & 15;
    const int qrow = qt * 64 + w * 16;

    bf16x8 ones;
#pragma unroll
    for (int j = 0; j < 8; j++) ones[j] = (short)0x3F80;   // bf16 1.0

    bf16x8 qf[2];
#pragma unroll
    for (int ks = 0; ks < 2; ks++)
        qf[ks] = *(const bf16x8*)(qb + baseK + (size_t)(qrow + n16) * HDIM + ks * 32 + quad * 8);

    f32x4 accO[4];
#pragma unroll
    for (int st = 0; st < 4; st++) accO[st] = (f32x4){0.f, 0.f, 0.f, 0.f};
    f32x4 accL = (f32x4){0.f, 0.f, 0.f, 0.f};

    bf16x8 kf[2][4];
#pragma unroll
    for (int st = 0; st < 4; st++)
#pragma unroll
        for (int ks = 0; ks < 2; ks++)
            kf[ks][st] = *(const bf16x8*)(kb + baseK + (size_t)(st * 16 + n16) * HDIM + ks * 32 + quad * 8);

    for (int kt = 0; kt <= qt; kt++) {
        bf16x8 vf[2][4];
        const u16* vbase = vt + baseV + kt * 64;
#pragma unroll
        for (int st = 0; st < 4; st++)
#pragma unroll
            for (int ks = 0; ks < 2; ks++)
                vf[ks][st] = *(const bf16x8*)(vbase + (size_t)(st * 16 + n16) * T_SEQ + ks * 32 + quad * 8);

        f32x4 S[4];
#pragma unroll
        for (int st = 0; st < 4; st++) S[st] = (f32x4){0.f, 0.f, 0.f, 0.f};
#pragma unroll
        for (int st = 0; st < 4; st++)
#pragma unroll
            for (int ks = 0; ks < 2; ks++)
                S[st] = __builtin_amdgcn_mfma_f32_16x16x32_bf16(qf[ks], kf[ks][st], S[st], 0, 0, 0);

        if (kt < qt) {   // prefetch next K under softmax
            const u16* kbase = kb + baseK + (size_t)(kt + 1) * 64 * HDIM;
#pragma unroll
            for (int st = 0; st < 4; st++)
#pragma unroll
                for (int ks = 0; ks < 2; ks++)
                    kf[ks][st] = *(const bf16x8*)(kbase + (st * 16 + n16) * HDIM + ks * 32 + quad * 8);
        }

        if (kt == qt) {   // diagonal tile: causal mask
            int qloc = w * 16 + quad * 4;
#pragma unroll
            for (int st = 0; st < 4; st++) {
                int kloc = st * 16 + n16;
#pragma unroll
                for (int r = 0; r < 4; r++)
                    if (kloc > qloc + r) S[st][r] = -INFINITY;
            }
        }

        // p = exp(s - 10) = exp2(1.4427*s - 14.427); bf16 by truncation (1 op)
#pragma unroll
        for (int st = 0; st < 4; st++)
#pragma unroll
            for (int r = 0; r < 4; r++) {
                float p = exp2f(__builtin_fmaf(S[st][r], 1.44269504f, -14.4269504f));
                Plds[w][quad * 4 + r][st * 16 + n16] = (u16)(__float_as_uint(p) >> 16);
            }
        asm volatile("s_waitcnt lgkmcnt(0)" ::: "memory");
        bf16x8 pf[2];
#pragma unroll
        for (int ks = 0; ks < 2; ks++)
            pf[ks] = *(const bf16x8*)(&Plds[w][n16][ks * 32 + quad * 8]);

#pragma unroll
        for (int st = 0; st < 4; st++)
#pragma unroll
            for (int ks = 0; ks < 2; ks++)
                accO[st] = __builtin_amdgcn_mfma_f32_16x16x32_bf16(pf[ks], vf[ks][st], accO[st], 0, 0, 0);
#pragma unroll
        for (int ks = 0; ks < 2; ks++)
            accL = __builtin_amdgcn_mfma_f32_16x16x32_bf16(pf[ks], ones, accL, 0, 0, 0);
    }

    // epilogue: normalize, transpose via Plds, full-line stores
#pragma unroll
    for (int r = 0; r < 4; r++) {
        float inv = 1.f / accL[r];
#pragma unroll
        for (int st = 0; st < 4; st++)
            Plds[w][quad * 4 + r][st * 16 + n16] = f2bf(accO[st][r] * inv);
    }
    asm volatile("s_waitcnt lgkmcnt(0)" ::: "memory");
    u16* dst = ob + ((size_t)(b * T_SEQ + qrow)) * 1024 + h * HDIM;
#pragma unroll
    for (int it = 0; it < 2; it++) {
        int row = it * 8 + (lane >> 3), col = (lane & 7) * 8;
        bf16x8 v = *(const bf16x8*)(&Plds[w][row][col]);
        *(bf16x8*)(dst + (size_t)row * 1024 + col) = v;
    }
}

extern "C" void kernel_launch(void* const* d_in, const int* in_sizes, int n_in,
                              void* d_out, int out_size, void* d_ws, size_t ws_size,
                              hipStream_t stream) {
    const void* x    = d_in[0];   // (2,2048,1024)
    const void* Wqkv = d_in[1];   // (3072,1024)
    const void* Wout = d_in[2];   // (1024,1024)

    const int Mtok = NB * T_SEQ;                                  // 4096
    const size_t n_x    = (size_t)Mtok * 1024;
    const size_t n_wqkv = (size_t)3072 * 1024;
    const size_t n_wout = (size_t)1024 * 1024;
    const size_t qkv_elems = (size_t)NB * NHEAD * T_SEQ * HDIM;   // 4,194,304

    u16* xb    = (u16*)d_ws;
    u16* wqkvb = xb + n_x;
    u16* woutb = wqkvb + n_wqkv;
    u16* qb    = woutb + n_wout;
    u16* kb    = qb + qkv_elems;
    u16* vt    = kb + qkv_elems;   // V stored transposed [b,h,d,t]
    u16* obuf  = vt + qkv_elems;
    int* flag  = (int*)(obuf + qkv_elems);

    detect_dtype<<<1, 64, 0, stream>>>((const uint32_t*)x, flag);

    to_bf16<<<1024, 256, 0, stream>>>(x,    xb,    (int)(n_x / 4),    flag);
    to_bf16<<<1024, 256, 0, stream>>>(Wqkv, wqkvb, (int)(n_wqkv / 4), flag);
    to_bf16<<<512,  256, 0, stream>>>(Wout, woutb, (int)(n_wout / 4), flag);

    gemm_bt_mfma<128, 0><<<dim3(3072 / 128, Mtok / 128), 256, 0, stream>>>(
        xb, wqkvb, 3072, 1024, qb, kb, vt, nullptr, nullptr, flag);

    attn_mfma<<<dim3(T_SEQ / 64, NB * NHEAD), 256, 0, stream>>>(qb, kb, vt, obuf);

    gemm_bt_mfma<64, 1><<<dim3(1024 / 64, Mtok / 64), 256, 0, stream>>>(
        obuf, woutb, 1024, 1024, nullptr, nullptr, nullptr,
        (u16*)d_out, (float*)d_out, flag);
}

// Round 7
// 203.576 us; speedup vs baseline: 2.0859x; 1.8768x over previous
//
#include <hip/hip_runtime.h>
#include <hip/hip_bf16.h>
#include <cstdint>

typedef unsigned short u16;
typedef __attribute__((ext_vector_type(8))) short bf16x8;
typedef __attribute__((ext_vector_type(4))) float f32x4;

#define T_SEQ 2048
#define NHEAD 16
#define HDIM  64
#define NB    2

__device__ __forceinline__ float bf2f(uint32_t h) { return __uint_as_float(h << 16); }
__device__ __forceinline__ u16 f2bf(float f) {
    uint32_t u = __float_as_uint(f);
    u += 0x7fffu + ((u >> 16) & 1u);
    return (u16)(u >> 16);
}

// async global->LDS, 16B per lane; LDS dest = wave-uniform base + lane*16
__device__ __forceinline__ void gl_lds16(const u16* g, u16* s) {
    __builtin_amdgcn_global_load_lds(
        (const __attribute__((address_space(1))) unsigned int*)g,
        (__attribute__((address_space(3))) unsigned int*)s, 16, 0, 0);
}

// Detect input dtype: bf16-packed data has low-u16 exponent fields clustered
// near 127; fp32 low halves are ~uniform mantissa bits.
__global__ void detect_dtype(const uint32_t* __restrict__ x, int* __restrict__ flag) {
    if (threadIdx.x == 0 && blockIdx.x == 0) {
        int cnt = 0;
        for (int i = 0; i < 1024; i++) {
            uint32_t lo = x[i] & 0xffffu;
            uint32_t e = (lo >> 7) & 0xffu;
            if (lo != 0u && e >= 110u && e <= 135u) cnt++;
        }
        *flag = (cnt > 614) ? 1 : 0;   // 1 = inputs bf16, 0 = fp32
    }
}

// vectorized conversion, 4 elements per thread
__global__ __launch_bounds__(256) void to_bf16(
    const void* __restrict__ src, u16* __restrict__ dst, int n4,
    const int* __restrict__ flag)
{
    int i = blockIdx.x * 256 + threadIdx.x;
    const int stride = gridDim.x * 256;
    if (*flag != 0) {
        const uint2* s = (const uint2*)src;
        uint2* d = (uint2*)dst;
        for (; i < n4; i += stride) d[i] = s[i];
    } else {
        const float4* s = (const float4*)src;
        for (; i < n4; i += stride) {
            float4 v = s[i];
            ushort4 o = { f2bf(v.x), f2bf(v.y), f2bf(v.z), f2bf(v.w) };
            *(ushort4*)(dst + (size_t)i * 4) = o;
        }
    }
}

// m97-pattern MFMA GEMM: C = A (MxK bf16 rm) * B^T (B NxK rm), fp32 accum.
// global_load_lds width-16 staging into unpadded [BM][64] LDS tiles with XOR
// swizzle (LDS chunk c of row r holds global chunk c^(r&7)) -> conflict-free
// stride-64 fragment reads. 4 waves in 2x2, no register staging buffers.
// MODE 0 (BM=128): scatter q [b,h,t,d] (x0.125), k [b,h,t,d], vT [b,h,d,t].
// MODE 1 (BM=64): row-major C; fp32 (flag==0) or bf16 path, full-line stores.
template<int BM, int MODE>
__global__ __launch_bounds__(256, 3) void gemm_bt_mfma(
    const u16* __restrict__ A, const u16* __restrict__ B,
    int N, int K,
    u16* __restrict__ qo, u16* __restrict__ ko, u16* __restrict__ vt,
    u16* __restrict__ outb16, float* __restrict__ outf32,
    const int* __restrict__ flag)
{
    constexpr int WM = BM / 2;
    constexpr int MI = WM / 16;
    constexpr int IA = BM / 32;   // global_load_lds instrs per wave per matrix
    constexpr int ST = 2 * BM * 64 * 2;                       // staging bytes
    constexpr int E16 = 4 * WM * 72 * 2;                      // u16 epilogue bytes
    constexpr int EF = (MODE == 1) ? 4 * WM * (WM + 4) * 4 : 0;  // f32 epilogue
    constexpr int SB = (ST > E16 ? ST : E16) > EF ? (ST > E16 ? ST : E16) : EF;
    __shared__ u16 smem[SB / 2];
    u16* As = smem;            // [BM][64]
    u16* Bs = smem + BM * 64;  // [BM][64]
    const int tid = threadIdx.x;
    const int bm = blockIdx.y * BM, bn = blockIdx.x * BM;
    const int w = tid >> 6, lane = tid & 63;
    const int wm = (w >> 1) * WM, wn = (w & 1) * WM;
    const int n16 = lane & 15, quad = lane >> 4;
    const int l8 = lane >> 3, c8 = lane & 7;

    f32x4 acc[MI][MI];
#pragma unroll
    for (int mi = 0; mi < MI; mi++)
#pragma unroll
        for (int ni = 0; ni < MI; ni++) acc[mi][ni] = (f32x4){0.f, 0.f, 0.f, 0.f};

    const int KT = K >> 6;
    for (int kt = 0; kt < KT; kt++) {
        const int k0 = kt << 6;
#pragma unroll
        for (int i = 0; i < IA; i++) {
            int rowblk = (i * 4 + w) * 8;
            int row = rowblk + l8;
            int gcol = (c8 ^ l8) * 8;   // XOR swizzle: LDS chunk c holds global chunk c^(row&7)
            gl_lds16(A + (size_t)(bm + row) * K + k0 + gcol, As + rowblk * 64);
            gl_lds16(B + (size_t)(bn + row) * K + k0 + gcol, Bs + rowblk * 64);
        }
        __syncthreads();   // drains vmcnt before barrier
#pragma unroll
        for (int ks = 0; ks < 2; ks++) {
            bf16x8 af[MI], bfr[MI];
#pragma unroll
            for (int mi = 0; mi < MI; mi++) {
                int row = wm + mi * 16 + n16;
                af[mi] = *(const bf16x8*)(As + row * 64 + (((ks * 4 + quad) ^ (n16 & 7)) * 8));
            }
#pragma unroll
            for (int ni = 0; ni < MI; ni++) {
                int row = wn + ni * 16 + n16;
                bfr[ni] = *(const bf16x8*)(Bs + row * 64 + (((ks * 4 + quad) ^ (n16 & 7)) * 8));
            }
#pragma unroll
            for (int mi = 0; mi < MI; mi++)
#pragma unroll
                for (int ni = 0; ni < MI; ni++)
                    acc[mi][ni] = __builtin_amdgcn_mfma_f32_16x16x32_bf16(
                        af[mi], bfr[ni], acc[mi][ni], 0, 0, 0);
        }
        __syncthreads();   // all reads done before next stage overwrites
    }

    // Epilogues: per-wave LDS transpose -> full-line stores.
    // C/D layout: col = n16, row = quad*4 + r (HW-verified m89/m91).
    if constexpr (MODE == 0) {
        u16* ep = smem + w * (WM * 72);
        const int which = (bn + wn) >> 10;            // wave-uniform: 0=q 1=k 2=v
        const int hq = ((bn + wn) & 1023) >> 6;
        const int bb = (bm + wm) >> 11;
        const int tb = (bm + wm) & (T_SEQ - 1);
        if (which == 2) {
            // transpose: ep rows are d, cols are t
#pragma unroll
            for (int mi = 0; mi < MI; mi++)
#pragma unroll
                for (int ni = 0; ni < MI; ni++)
#pragma unroll
                    for (int r = 0; r < 4; r++)
                        ep[(ni * 16 + n16) * 72 + mi * 16 + quad * 4 + r] = f2bf(acc[mi][ni][r]);
            asm volatile("s_waitcnt lgkmcnt(0)" ::: "memory");
            u16* dst = vt + ((size_t)(bb * NHEAD + hq) * HDIM) * T_SEQ + tb;
#pragma unroll
            for (int it = 0; it < 8; it++) {
                int row = it * 8 + l8, col = c8 * 8;
                bf16x8 v = *(const bf16x8*)(ep + row * 72 + col);
                *(bf16x8*)(dst + (size_t)row * T_SEQ + col) = v;
            }
        } else {
            const float sc = which ? 1.f : 0.125f;
#pragma unroll
            for (int mi = 0; mi < MI; mi++)
#pragma unroll
                for (int ni = 0; ni < MI; ni++)
#pragma unroll
                    for (int r = 0; r < 4; r++)
                        ep[(mi * 16 + quad * 4 + r) * 72 + ni * 16 + n16] = f2bf(acc[mi][ni][r] * sc);
            asm volatile("s_waitcnt lgkmcnt(0)" ::: "memory");
            u16* dst = (which ? ko : qo) + ((size_t)(bb * NHEAD + hq) * T_SEQ + tb) * HDIM;
#pragma unroll
            for (int it = 0; it < 8; it++) {
                int row = it * 8 + l8, col = c8 * 8;
                bf16x8 v = *(const bf16x8*)(ep + row * 72 + col);
                *(bf16x8*)(dst + (size_t)row * HDIM + col) = v;
            }
        }
    } else {
        if (*flag == 0) {
            // fp32 output (live path): float4 full-line stores via LDS transpose
            float* epf = (float*)smem + w * (WM * (WM + 4));
#pragma unroll
            for (int mi = 0; mi < MI; mi++)
#pragma unroll
                for (int ni = 0; ni < MI; ni++)
#pragma unroll
                    for (int r = 0; r < 4; r++)
                        epf[(mi * 16 + quad * 4 + r) * (WM + 4) + ni * 16 + n16] = acc[mi][ni][r];
            asm volatile("s_waitcnt lgkmcnt(0)" ::: "memory");
            constexpr int LPR = WM / 4;                 // lanes per row (float4)
            constexpr int RPI = 64 / LPR;               // rows per instruction
#pragma unroll
            for (int it = 0; it < WM / RPI; it++) {
                int row = it * RPI + lane / LPR, col = (lane % LPR) * 4;
                float4 v = *(const float4*)(epf + row * (WM + 4) + col);
                *(float4*)(outf32 + (size_t)(bm + wm + row) * N + bn + wn + col) = v;
            }
        } else {
            u16* ep = smem + w * (WM * 72);
#pragma unroll
            for (int mi = 0; mi < MI; mi++)
#pragma unroll
                for (int ni = 0; ni < MI; ni++)
#pragma unroll
                    for (int r = 0; r < 4; r++)
                        ep[(mi * 16 + quad * 4 + r) * 72 + ni * 16 + n16] = f2bf(acc[mi][ni][r]);
            asm volatile("s_waitcnt lgkmcnt(0)" ::: "memory");
            constexpr int LPR = WM / 8;
            constexpr int RPI = 64 / LPR;
#pragma unroll
            for (int it = 0; it < WM / RPI; it++) {
                int row = it * RPI + lane / LPR, col = (lane % LPR) * 8;
                bf16x8 v = *(const bf16x8*)(ep + row * 72 + col);
                *(bf16x8*)(outb16 + (size_t)(bm + wm + row) * N + bn + wn + col) = v;
            }
        }
    }
}

// MFMA flash attention with cooperative LDS staging of K/V (once per block,
// not per wave), max-free softmax (p = exp(s-10), offset cancels in o/l),
// denominators via mfma(P, ones). Paired q-tiles (i, NT-1-i): uniform 33
// kt-units per block, 512 blocks = 2/CU fully co-resident.
// Loop: bar1 -> ds_read kf/vf -> bar2 -> async stage(kt+1) -> compute.
__global__ __launch_bounds__(256, 2) void attn_mfma(
    const u16* __restrict__ qb, const u16* __restrict__ kb,
    const u16* __restrict__ vt, u16* __restrict__ ob)
{
    __shared__ u16 Ks[64 * 64];        // [t_local][d], XOR-swizzled chunks
    __shared__ u16 Vs[64 * 64];        // [d][t_local], XOR-swizzled chunks
    __shared__ u16 Plds[4][16][72];
    const int pair = blockIdx.x;       // 0..NT/2-1
    const int bh = blockIdx.y;
    const int w = threadIdx.x >> 6, lane = threadIdx.x & 63;
    const int n16 = lane & 15, quad = lane >> 4;
    const int l8 = lane >> 3, c8 = lane & 7;
    const size_t baseK = (size_t)bh * T_SEQ * HDIM;   // [t][d]
    const size_t baseV = (size_t)bh * HDIM * T_SEQ;   // [d][t]
    const int NT = T_SEQ / 64;         // 32
    const int b = bh >> 4, h = bh & 15;

    bf16x8 ones;
#pragma unroll
    for (int j = 0; j < 8; j++) ones[j] = (short)0x3F80;   // bf16 1.0

    // staging: each wave covers 2 row-groups of 8 rows per matrix
    auto stage = [&](int kt) {
#pragma unroll
        for (int i = 0; i < 2; i++) {
            int rowblk = (i * 4 + w) * 8;
            int row = rowblk + l8;
            int gc = (c8 ^ l8) * 8;    // XOR swizzle
            gl_lds16(kb + baseK + (size_t)(kt * 64 + row) * HDIM + gc, Ks + rowblk * 64);
            gl_lds16(vt + baseV + (size_t)row * T_SEQ + kt * 64 + gc, Vs + rowblk * 64);
        }
    };

    for (int half = 0; half < 2; half++) {
        const int qt = half ? pair : (NT - 1 - pair);   // big tile first
        const int qrow = qt * 64 + w * 16;

        bf16x8 qf[2];
#pragma unroll
        for (int ks = 0; ks < 2; ks++)
            qf[ks] = *(const bf16x8*)(qb + baseK + (size_t)(qrow + n16) * HDIM + ks * 32 + quad * 8);

        f32x4 accO[4];
#pragma unroll
        for (int st = 0; st < 4; st++) accO[st] = (f32x4){0.f, 0.f, 0.f, 0.f};
        f32x4 accL = (f32x4){0.f, 0.f, 0.f, 0.f};

        stage(0);
        for (int kt = 0; kt <= qt; kt++) {
            __syncthreads();   // stage(kt) complete (drains vmcnt)

            bf16x8 kf[2][4], vf[2][4];
#pragma unroll
            for (int st = 0; st < 4; st++)
#pragma unroll
                for (int ks = 0; ks < 2; ks++) {
                    int off = (st * 16 + n16) * 64 + (((ks * 4 + quad) ^ (n16 & 7)) * 8);
                    kf[ks][st] = *(const bf16x8*)(Ks + off);
                    vf[ks][st] = *(const bf16x8*)(Vs + off);
                }
            __syncthreads();   // all fragments in registers; K/V LDS free

            if (kt < qt) stage(kt + 1);   // async, lands during compute below

            f32x4 S[4];
#pragma unroll
            for (int st = 0; st < 4; st++) S[st] = (f32x4){0.f, 0.f, 0.f, 0.f};
#pragma unroll
            for (int st = 0; st < 4; st++)
#pragma unroll
                for (int ks = 0; ks < 2; ks++)
                    S[st] = __builtin_amdgcn_mfma_f32_16x16x32_bf16(qf[ks], kf[ks][st], S[st], 0, 0, 0);

            if (kt == qt) {   // diagonal tile: causal mask
                int qloc = w * 16 + quad * 4;
#pragma unroll
                for (int st = 0; st < 4; st++) {
                    int kloc = st * 16 + n16;
#pragma unroll
                    for (int r = 0; r < 4; r++)
                        if (kloc > qloc + r) S[st][r] = -INFINITY;
                }
            }

            // p = exp(s - 10) = exp2(1.4427*s - 14.427); bf16 by truncation
#pragma unroll
            for (int st = 0; st < 4; st++)
#pragma unroll
                for (int r = 0; r < 4; r++) {
                    float p = exp2f(__builtin_fmaf(S[st][r], 1.44269504f, -14.4269504f));
                    Plds[w][quad * 4 + r][st * 16 + n16] = (u16)(__float_as_uint(p) >> 16);
                }
            asm volatile("s_waitcnt lgkmcnt(0)" ::: "memory");
            bf16x8 pf[2];
#pragma unroll
            for (int ks = 0; ks < 2; ks++)
                pf[ks] = *(const bf16x8*)(&Plds[w][n16][ks * 32 + quad * 8]);

#pragma unroll
            for (int st = 0; st < 4; st++)
#pragma unroll
                for (int ks = 0; ks < 2; ks++)
                    accO[st] = __builtin_amdgcn_mfma_f32_16x16x32_bf16(pf[ks], vf[ks][st], accO[st], 0, 0, 0);
#pragma unroll
            for (int ks = 0; ks < 2; ks++)
                accL = __builtin_amdgcn_mfma_f32_16x16x32_bf16(pf[ks], ones, accL, 0, 0, 0);
        }

        // epilogue: normalize, transpose via Plds (wave-private), line stores
#pragma unroll
        for (int r = 0; r < 4; r++) {
            float inv = 1.f / accL[r];
#pragma unroll
            for (int st = 0; st < 4; st++)
                Plds[w][quad * 4 + r][st * 16 + n16] = f2bf(accO[st][r] * inv);
        }
        asm volatile("s_waitcnt lgkmcnt(0)" ::: "memory");
        u16* dst = ob + ((size_t)(b * T_SEQ + qrow)) * 1024 + h * HDIM;
#pragma unroll
        for (int it = 0; it < 2; it++) {
            int row = it * 8 + l8, col = c8 * 8;
            bf16x8 v = *(const bf16x8*)(&Plds[w][row][col]);
            *(bf16x8*)(dst + (size_t)row * 1024 + col) = v;
        }
    }
}

extern "C" void kernel_launch(void* const* d_in, const int* in_sizes, int n_in,
                              void* d_out, int out_size, void* d_ws, size_t ws_size,
                              hipStream_t stream) {
    const void* x    = d_in[0];   // (2,2048,1024)
    const void* Wqkv = d_in[1];   // (3072,1024)
    const void* Wout = d_in[2];   // (1024,1024)

    const int Mtok = NB * T_SEQ;                                  // 4096
    const size_t n_x    = (size_t)Mtok * 1024;
    const size_t n_wqkv = (size_t)3072 * 1024;
    const size_t n_wout = (size_t)1024 * 1024;
    const size_t qkv_elems = (size_t)NB * NHEAD * T_SEQ * HDIM;   // 4,194,304

    u16* xb    = (u16*)d_ws;
    u16* wqkvb = xb + n_x;
    u16* woutb = wqkvb + n_wqkv;
    u16* qb    = woutb + n_wout;
    u16* kb    = qb + qkv_elems;
    u16* vt    = kb + qkv_elems;   // V stored transposed [b,h,d,t]
    u16* obuf  = vt + qkv_elems;
    int* flag  = (int*)(obuf + qkv_elems);

    detect_dtype<<<1, 64, 0, stream>>>((const uint32_t*)x, flag);

    to_bf16<<<1024, 256, 0, stream>>>(x,    xb,    (int)(n_x / 4),    flag);
    to_bf16<<<1024, 256, 0, stream>>>(Wqkv, wqkvb, (int)(n_wqkv / 4), flag);
    to_bf16<<<512,  256, 0, stream>>>(Wout, woutb, (int)(n_wout / 4), flag);

    gemm_bt_mfma<128, 0><<<dim3(3072 / 128, Mtok / 128), 256, 0, stream>>>(
        xb, wqkvb, 3072, 1024, qb, kb, vt, nullptr, nullptr, flag);

    attn_mfma<<<dim3(T_SEQ / 128, NB * NHEAD), 256, 0, stream>>>(qb, kb, vt, obuf);

    gemm_bt_mfma<64, 1><<<dim3(1024 / 64, Mtok / 64), 256, 0, stream>>>(
        obuf, woutb, 1024, 1024, nullptr, nullptr, nullptr,
        (u16*)d_out, (float*)d_out, flag);
}